// Round 10
// baseline (305.566 us; speedup 1.0000x reference)
//
#include <hip/hip_runtime.h>
#include <hip/hip_bf16.h>

#define BSH 9
#define BSZ 512    // nodes per bucket
#define CAP 17408  // edge capacity per bucket (mean 16384 + 8 sigma) -> no hist/scan needed

__device__ __forceinline__ unsigned short f2bf(float f) {  // RN-even fp32->bf16
    unsigned u = __float_as_uint(f);
    u += 0x7fffu + ((u >> 16) & 1u);
    return (unsigned short)(u >> 16);
}
__device__ __forceinline__ float b2f(unsigned short v) {
    return __uint_as_float((unsigned)v << 16);
}

// init bucket cursors to fixed bases
__global__ void init_k(int* __restrict__ curD, int* __restrict__ curS, int nbk) {
    int i = threadIdx.x;
    if (i < nbk) { curD[i] = i * CAP; curS[i] = i * CAP; }
}

// ---------------- fused: GEMM1 (row-major LDS x-tile + scalar W) + edge scatter ----------------
// blocks [0, nG1): gemm (256 rows/block, thread = 1 row, 16 cols in acc).
// blocks [nG1, nG1+NBLK): scatter (aliases the gemm LDS tile for its counters).
// pairs packed: (src << 9) | (dst & 511).  sbuf: low 9 bits of src (ushort).

#define KCH 16
#define XTS 20  // 80 B rows: b128-aligned; bank-start 16*(5t mod 8) -> uniform 8 lanes/slot (floor)

__global__ __launch_bounds__(256) void fused_gs_k(
    const float* __restrict__ X, const float* __restrict__ W, const float* __restrict__ B,
    float* __restrict__ H, int n, int nG1,
    const int* __restrict__ src, const int* __restrict__ dst, int E, int chunk,
    int* __restrict__ curD, int* __restrict__ curS,
    unsigned int* __restrict__ pairs, unsigned short* __restrict__ sbuf, int nbk) {
    __shared__ float xt[256 * XTS];   // 20.5 KB; scatter path aliases first 4 KB
    int t = threadIdx.x;

    if ((int)blockIdx.x < nG1) {
        // ---- GEMM path ----
        int rowBase = blockIdx.x * 256;
        int myRow = rowBase + t;
        int srow = t >> 2, skq = t & 3;   // staging: row = p*64 + srow, k-quad skq (4 lanes = 64 B of one row)

        float acc[16];
#pragma unroll
        for (int c = 0; c < 16; c++) acc[c] = 0.f;

        float4 xreg[4];
#pragma unroll
        for (int p = 0; p < 4; p++) {
            int gr = rowBase + p * 64 + srow;
            xreg[p] = (gr < n) ? *(const float4*)&X[(size_t)gr * 512 + skq * 4]
                               : float4{0.f, 0.f, 0.f, 0.f};
        }

        for (int ch = 0; ch < 32; ++ch) {
#pragma unroll
            for (int p = 0; p < 4; p++) {
                int r = p * 64 + srow;
                *(float4*)&xt[r * XTS + skq * 4] = xreg[p];
            }
            __syncthreads();

            if (ch < 31) {
                int k0n = (ch + 1) * KCH;
#pragma unroll
                for (int p = 0; p < 4; p++) {
                    int gr = rowBase + p * 64 + srow;
                    xreg[p] = (gr < n) ? *(const float4*)&X[(size_t)gr * 512 + k0n + skq * 4]
                                       : float4{0.f, 0.f, 0.f, 0.f};
                }
            }

#pragma unroll
            for (int g = 0; g < 4; g++) {
                float4 xv = *(const float4*)&xt[t * XTS + g * 4];
                int kb = ch * KCH + g * 4;
#pragma unroll
                for (int e = 0; e < 4; e++) {
                    // wave-uniform address -> scalar (SMEM) loads, no LDS traffic
                    const float4* wr = (const float4*)&W[(size_t)(kb + e) * 16];
                    float xs = (e == 0) ? xv.x : (e == 1) ? xv.y : (e == 2) ? xv.z : xv.w;
                    float4 w0 = wr[0], w1 = wr[1], w2 = wr[2], w3 = wr[3];
                    acc[0]  = fmaf(xs, w0.x, acc[0]);  acc[1]  = fmaf(xs, w0.y, acc[1]);
                    acc[2]  = fmaf(xs, w0.z, acc[2]);  acc[3]  = fmaf(xs, w0.w, acc[3]);
                    acc[4]  = fmaf(xs, w1.x, acc[4]);  acc[5]  = fmaf(xs, w1.y, acc[5]);
                    acc[6]  = fmaf(xs, w1.z, acc[6]);  acc[7]  = fmaf(xs, w1.w, acc[7]);
                    acc[8]  = fmaf(xs, w2.x, acc[8]);  acc[9]  = fmaf(xs, w2.y, acc[9]);
                    acc[10] = fmaf(xs, w2.z, acc[10]); acc[11] = fmaf(xs, w2.w, acc[11]);
                    acc[12] = fmaf(xs, w3.x, acc[12]); acc[13] = fmaf(xs, w3.y, acc[13]);
                    acc[14] = fmaf(xs, w3.z, acc[14]); acc[15] = fmaf(xs, w3.w, acc[15]);
                }
            }
            __syncthreads();
        }

        if (myRow < n) {
            const float4* bp = (const float4*)B;
            float4 b0 = bp[0], b1 = bp[1], b2 = bp[2], b3 = bp[3];
            float4* o = (float4*)&H[(size_t)myRow * 16];
            o[0] = float4{acc[0] + b0.x, acc[1] + b0.y, acc[2] + b0.z, acc[3] + b0.w};
            o[1] = float4{acc[4] + b1.x, acc[5] + b1.y, acc[6] + b1.z, acc[7] + b1.w};
            o[2] = float4{acc[8] + b2.x, acc[9] + b2.y, acc[10] + b2.z, acc[11] + b2.w};
            o[3] = float4{acc[12] + b3.x, acc[13] + b3.y, acc[14] + b3.z, acc[15] + b3.w};
        }
    } else {
        // ---- scatter path: local hist -> reserve range -> scatter (counters alias xt) ----
        int* lhD = (int*)xt;
        int* lhS = lhD + 256;
        int* bD  = lhD + 512;
        int* bS  = lhD + 768;
        int bb = blockIdx.x - nG1;
        lhD[t] = 0; lhS[t] = 0;
        __syncthreads();
        int lo = bb * chunk, hi = min(E, lo + chunk);
        for (int i = lo + t; i < hi; i += 256) {
            atomicAdd(&lhD[dst[i] >> BSH], 1);
            atomicAdd(&lhS[src[i] >> BSH], 1);
        }
        __syncthreads();
        if (t < nbk) {
            bD[t] = lhD[t] ? atomicAdd(&curD[t], lhD[t]) : 0;
            bS[t] = lhS[t] ? atomicAdd(&curS[t], lhS[t]) : 0;
        }
        __syncthreads();
        lhD[t] = 0; lhS[t] = 0;
        __syncthreads();
        for (int i = lo + t; i < hi; i += 256) {  // chunk L2-hot from first loop
            int s = src[i], d = dst[i];
            int pd = bD[d >> BSH] + atomicAdd(&lhD[d >> BSH], 1);
            pairs[pd] = ((unsigned int)s << BSH) | (unsigned int)(d & (BSZ - 1));
            int ps = bS[s >> BSH] + atomicAdd(&lhS[s >> BSH], 1);
            sbuf[ps] = (unsigned short)(s & (BSZ - 1));
        }
    }
}

// ---------------- dinv (src-degree) + scale h1 -> bf16 hw1 (hw1 = dinv * h1) ----------------

__global__ __launch_bounds__(256) void dinvScale_k(const unsigned short* __restrict__ sbuf,
                                                   const int* __restrict__ curS,
                                                   const float* __restrict__ h1,
                                                   float* __restrict__ dinv,
                                                   unsigned short* __restrict__ hw1, int n) {
    __shared__ int cnt[BSZ];
    __shared__ float dl[BSZ];
    int b = blockIdx.x, t = threadIdx.x;
    cnt[t] = 0; cnt[t + 256] = 0;
    __syncthreads();
    int lo = b * CAP, hi = curS[b];
    for (int i = lo + t; i < hi; i += 256) atomicAdd(&cnt[sbuf[i]], 1);
    __syncthreads();
    int n0 = b * BSZ + t, n1 = n0 + 256;
    float d0 = rsqrtf((float)(1 + cnt[t]));
    float d1 = rsqrtf((float)(1 + cnt[t + 256]));
    dl[t] = d0; dl[t + 256] = d1;
    if (n0 < n) dinv[n0] = d0;
    if (n1 < n) dinv[n1] = d1;
    __syncthreads();
    int rows = min(BSZ, n - b * BSZ);
    int lim4 = rows * 4;                      // float4 units in this bucket
    size_t base = (size_t)b * BSZ * 16;
#pragma unroll
    for (int j = 0; j < 8; j++) {
        int i4 = j * 256 + t;
        if (i4 < lim4) {
            float4 v = *(const float4*)&h1[base + (size_t)i4 * 4];
            float d = dl[i4 >> 2];
            ushort4 u;
            u.x = f2bf(v.x * d); u.y = f2bf(v.y * d);
            u.z = f2bf(v.z * d); u.w = f2bf(v.w * d);
            *(ushort4*)&hw1[base + (size_t)i4 * 4] = u;
        }
    }
}

// ---------------- CSR build + rowsum[d] = dd*(dd + sum_{s in N_in(d)} dinv[s]) ----------------

__global__ __launch_bounds__(256) void build_k(const unsigned int* __restrict__ pairs,
                                               const int* __restrict__ curD,
                                               const float* __restrict__ dinv,
                                               int* __restrict__ rowPtr, int* __restrict__ cntD,
                                               int* __restrict__ col, float* __restrict__ rowsum,
                                               int n) {
    __shared__ int cnt[BSZ];
    __shared__ int off[BSZ];
    __shared__ int ps[256];
    __shared__ float lsum[BSZ];
    int b = blockIdx.x, t = threadIdx.x;
    cnt[t] = 0; cnt[t + 256] = 0;
    lsum[t] = 0.f; lsum[t + 256] = 0.f;
    __syncthreads();
    int lo = b * CAP, hi = curD[b];
    for (int i = lo + t; i < hi; i += 256) atomicAdd(&cnt[pairs[i] & (BSZ - 1)], 1);
    __syncthreads();
    int c0 = cnt[2 * t], c1 = cnt[2 * t + 1];
    ps[t] = c0 + c1;
    __syncthreads();
    for (int o = 1; o < 256; o <<= 1) {
        int u = (t >= o) ? ps[t - o] : 0; __syncthreads();
        ps[t] += u; __syncthreads();
    }
    int ex = ps[t] - (c0 + c1);
    off[2 * t] = ex; off[2 * t + 1] = ex + c0;
    __syncthreads();
    int n0 = b * BSZ + t, n1 = n0 + 256;
    if (n0 < n) { rowPtr[n0] = lo + off[t]; cntD[n0] = cnt[t]; }
    if (n1 < n) { rowPtr[n1] = lo + off[t + 256]; cntD[n1] = cnt[t + 256]; }
    __syncthreads();
    cnt[t] = 0; cnt[t + 256] = 0;
    __syncthreads();
    for (int i = lo + t; i < hi; i += 256) {  // L2-hot re-read
        unsigned int p = pairs[i];
        int l = p & (BSZ - 1);
        int s = (int)(p >> BSH);
        int pos = lo + off[l] + atomicAdd(&cnt[l], 1);
        col[pos] = s;
        atomicAdd(&lsum[l], dinv[s]);
    }
    __syncthreads();
    if (n0 < n) { float dd = dinv[n0]; rowsum[n0] = dd * (dd + lsum[t]); }
    if (n1 < n) { float dd = dinv[n1]; rowsum[n1] = dd * (dd + lsum[t + 256]); }
}

// ---------------- aggregation on premultiplied bf16 features ----------------
// A[d] = hw[d] + sum_s hw[s];  4 lanes/edge, ushort4 (8B) per lane, 2-way unroll

__device__ __forceinline__ float4 gather_agg(const unsigned short* __restrict__ HW,
                                             const int* __restrict__ col,
                                             int start, int c, int node, int eg, int q) {
    float4 a0 = {0.f, 0.f, 0.f, 0.f}, a1 = {0.f, 0.f, 0.f, 0.f};
    int i = eg;
    for (; i + 16 < c; i += 32) {
        int s0 = col[start + i];
        int s1 = col[start + i + 16];
        ushort4 u0 = *(const ushort4*)&HW[(size_t)s0 * 16 + q * 4];
        ushort4 u1 = *(const ushort4*)&HW[(size_t)s1 * 16 + q * 4];
        a0.x += b2f(u0.x); a0.y += b2f(u0.y); a0.z += b2f(u0.z); a0.w += b2f(u0.w);
        a1.x += b2f(u1.x); a1.y += b2f(u1.y); a1.z += b2f(u1.z); a1.w += b2f(u1.w);
    }
    if (i < c) {
        int s0 = col[start + i];
        ushort4 u0 = *(const ushort4*)&HW[(size_t)s0 * 16 + q * 4];
        a0.x += b2f(u0.x); a0.y += b2f(u0.y); a0.z += b2f(u0.z); a0.w += b2f(u0.w);
    }
    if (eg == 0) {  // self loop
        ushort4 us = *(const ushort4*)&HW[(size_t)node * 16 + q * 4];
        a1.x += b2f(us.x); a1.y += b2f(us.y); a1.z += b2f(us.z); a1.w += b2f(us.w);
    }
    a0.x += a1.x; a0.y += a1.y; a0.z += a1.z; a0.w += a1.w;
#pragma unroll
    for (int off = 4; off < 64; off <<= 1) {
        a0.x += __shfl_xor(a0.x, off, 64);
        a0.y += __shfl_xor(a0.y, off, 64);
        a0.z += __shfl_xor(a0.z, off, 64);
        a0.w += __shfl_xor(a0.w, off, 64);
    }
    return a0;
}

// layer-1: out = bf16( dinv * relu(dinv * A) )   (premultiplied for layer 2)
__global__ void agg1_k(const unsigned short* __restrict__ HW, const float* __restrict__ dinv,
                       const int* __restrict__ col, const int* __restrict__ rowPtr,
                       const int* __restrict__ cnt, unsigned short* __restrict__ out, int n) {
    int lane = threadIdx.x & 63;
    int node = (blockIdx.x * blockDim.x + threadIdx.x) >> 6;
    if (node >= n) return;
    int eg = lane >> 2, q = lane & 3;
    int start = rowPtr[node], c = cnt[node];
    float4 A = gather_agg(HW, col, start, c, node, eg, q);
    if (eg == 0) {
        float dd = dinv[node];
        ushort4 u;
        u.x = f2bf(dd * fmaxf(dd * A.x, 0.f)); u.y = f2bf(dd * fmaxf(dd * A.y, 0.f));
        u.z = f2bf(dd * fmaxf(dd * A.z, 0.f)); u.w = f2bf(dd * fmaxf(dd * A.w, 0.f));
        *(ushort4*)&out[(size_t)node * 16 + q * 4] = u;
    }
}

// layer-2 aggregation fused with logits + log_softmax
__global__ void agg2f_k(const unsigned short* __restrict__ HW, const float* __restrict__ dinv,
                        const int* __restrict__ col, const int* __restrict__ rowPtr,
                        const int* __restrict__ cnt, const float* __restrict__ rowsum,
                        const float* __restrict__ W2, const float* __restrict__ B2,
                        float* __restrict__ out, int n, int nc) {
    int lane = threadIdx.x & 63;
    int node = (blockIdx.x * blockDim.x + threadIdx.x) >> 6;
    if (node >= n) return;
    int eg = lane >> 2, q = lane & 3;
    int start = rowPtr[node], c = cnt[node];
    float4 A = gather_agg(HW, col, start, c, node, eg, q);
    float dd = dinv[node];
    A.x *= dd; A.y *= dd; A.z *= dd; A.w *= dd;   // a2 features, all lanes hold quad q
    float f[16];
    f[0]  = __shfl(A.x, 0, 64); f[1]  = __shfl(A.y, 0, 64);
    f[2]  = __shfl(A.z, 0, 64); f[3]  = __shfl(A.w, 0, 64);
    f[4]  = __shfl(A.x, 1, 64); f[5]  = __shfl(A.y, 1, 64);
    f[6]  = __shfl(A.z, 1, 64); f[7]  = __shfl(A.w, 1, 64);
    f[8]  = __shfl(A.x, 2, 64); f[9]  = __shfl(A.y, 2, 64);
    f[10] = __shfl(A.z, 2, 64); f[11] = __shfl(A.w, 2, 64);
    f[12] = __shfl(A.x, 3, 64); f[13] = __shfl(A.y, 3, 64);
    f[14] = __shfl(A.z, 3, 64); f[15] = __shfl(A.w, 3, 64);
    float logit = -1e30f;
    if (lane < nc) {
        logit = rowsum[node] * B2[lane];
#pragma unroll
        for (int k = 0; k < 16; k++) logit = fmaf(f[k], W2[k * nc + lane], logit);
    }
    float m = logit;
#pragma unroll
    for (int off = 1; off < 64; off <<= 1) m = fmaxf(m, __shfl_xor(m, off, 64));
    float e = (lane < nc) ? __expf(logit - m) : 0.f;
    float s = e;
#pragma unroll
    for (int off = 1; off < 64; off <<= 1) s += __shfl_xor(s, off, 64);
    if (lane < nc) out[(size_t)node * nc + lane] = logit - m - __logf(s);
}

// ---------------- launch ----------------

extern "C" void kernel_launch(void* const* d_in, const int* in_sizes, int n_in,
                              void* d_out, int out_size, void* d_ws, size_t ws_size,
                              hipStream_t stream) {
    const float* X  = (const float*)d_in[0];
    const int*   EI = (const int*)d_in[1];
    const float* W1 = (const float*)d_in[2];
    const float* B1 = (const float*)d_in[3];
    const float* W2 = (const float*)d_in[4];
    const float* B2 = (const float*)d_in[5];
    float* out = (float*)d_out;

    int NH = in_sizes[3];            // 16
    int NC = in_sizes[5];            // 40
    int NF = in_sizes[2] / NH;       // 512
    int n  = in_sizes[0] / NF;       // 100000
    int E  = in_sizes[1] / 2;        // 3200000
    const int* src = EI;
    const int* dst = EI + E;
    int nbk = (n + BSZ - 1) >> BSH;  // 196

    char* ws = (char*)d_ws;
    size_t o = 0;
    auto alloc = [&](size_t bytes) { size_t r = o; o = (o + bytes + 255) & ~(size_t)255; return r; };
    size_t o_dinv   = alloc((size_t)n * 4);
    size_t o_rowPtr = alloc((size_t)n * 4);
    size_t o_cntD   = alloc((size_t)n * 4);
    size_t o_rsum   = alloc((size_t)n * 4);
    size_t o_curD   = alloc(1024);
    size_t o_curS   = alloc(1024);
    size_t o_pairs  = alloc((size_t)nbk * CAP * 4);
    size_t o_sbuf   = alloc((size_t)nbk * CAP * 2);
    size_t o_col    = alloc((size_t)nbk * CAP * 4);
    size_t o_h1     = alloc((size_t)n * 16 * 4);   // fp32 gemm out (pre-scale)
    size_t o_hw1    = alloc((size_t)n * 16 * 2);   // bf16 dinv*h1
    size_t o_a1w    = alloc((size_t)n * 16 * 2);   // bf16 dinv*relu(layer1)

    float* dinv  = (float*)(ws + o_dinv);
    int* rowPtr  = (int*)(ws + o_rowPtr);
    int* cntD    = (int*)(ws + o_cntD);
    float* rsum  = (float*)(ws + o_rsum);
    int* curD    = (int*)(ws + o_curD);
    int* curS    = (int*)(ws + o_curS);
    unsigned int* pairs   = (unsigned int*)(ws + o_pairs);
    unsigned short* sbuf  = (unsigned short*)(ws + o_sbuf);
    int* col     = (int*)(ws + o_col);
    float* h1    = (float*)(ws + o_h1);
    unsigned short* hw1 = (unsigned short*)(ws + o_hw1);
    unsigned short* a1w = (unsigned short*)(ws + o_a1w);

    init_k<<<1, 256, 0, stream>>>(curD, curS, nbk);

    const int NBLK = 1536;
    int chunk = (E + NBLK - 1) / NBLK;
    int nG1 = (n + 255) / 256;
    fused_gs_k<<<nG1 + NBLK, 256, 0, stream>>>(X, W1, B1, h1, n, nG1,
                                               src, dst, E, chunk, curD, curS,
                                               pairs, sbuf, nbk);
    dinvScale_k<<<nbk, 256, 0, stream>>>(sbuf, curS, h1, dinv, hw1, n);
    build_k<<<nbk, 256, 0, stream>>>(pairs, curD, dinv, rowPtr, cntD, col, rsum, n);

    int aggGrid = (n + 3) / 4;  // one wave per node, 4 waves/block
    agg1_k<<<aggGrid, 256, 0, stream>>>(hw1, dinv, col, rowPtr, cntD, a1w, n);
    agg2f_k<<<aggGrid, 256, 0, stream>>>(a1w, dinv, col, rowPtr, cntD, rsum, W2, B2, out, n, NC);
}

// Round 11
// 270.603 us; speedup vs baseline: 1.1292x; 1.1292x over previous
//
#include <hip/hip_runtime.h>
#include <hip/hip_bf16.h>

#define BSH 9
#define BSZ 512    // nodes per bucket
#define CAP 17408  // edge capacity per bucket (mean 16384 + 8 sigma)
#define CHK 4096   // edges per scatter block

__device__ __forceinline__ unsigned short f2bf(float f) {  // RN-even fp32->bf16
    unsigned u = __float_as_uint(f);
    u += 0x7fffu + ((u >> 16) & 1u);
    return (unsigned short)(u >> 16);
}
__device__ __forceinline__ float b2f(unsigned short v) {
    return __uint_as_float((unsigned)v << 16);
}

// init bucket cursors to fixed bases
__global__ void init_k(int* __restrict__ curD, int* __restrict__ curS, int nbk) {
    int i = threadIdx.x;
    if (i < nbk) { curD[i] = i * CAP; curS[i] = i * CAP; }
}

// ---------------- fused: GEMM1 (R9 structure) + LDS-staged bucket-sort scatter ----------------
// blocks [0, nG1): gemm.  blocks [nG1, nG1+NBLK): scatter.
// pairs packed: (src << 9) | (dst & 511).  sbuf: low 9 bits of src (ushort).

#define KCH 32
#define XTS 258

__global__ __launch_bounds__(256) void fused_gs_k(
    const float* __restrict__ X, const float* __restrict__ W, const float* __restrict__ B,
    float* __restrict__ H, int n, int nG1,
    const int* __restrict__ src, const int* __restrict__ dst, int E,
    int* __restrict__ curD, int* __restrict__ curS,
    unsigned int* __restrict__ pairs, unsigned short* __restrict__ sbuf, int nbk) {
    __shared__ char smem[KCH * XTS * 4];   // 33 KB union (gemm tile | scatter stage)
    int t = threadIdx.x;

    if ((int)blockIdx.x < nG1) {
        // ---- GEMM path (R9: LDS-staged X transposed, W via wave-uniform scalar loads) ----
        float* xt = (float*)smem;
        int rowBase = blockIdx.x * 256;
        int myRow = rowBase + t;
        int srow = t >> 3, skq = t & 7;   // staging: row = p*32+srow, k-quad = skq

        float acc[16];
#pragma unroll
        for (int c = 0; c < 16; c++) acc[c] = 0.f;

        float4 xreg[8];
#pragma unroll
        for (int p = 0; p < 8; p++) {
            int gr = rowBase + p * 32 + srow;
            xreg[p] = (gr < n) ? *(const float4*)&X[(size_t)gr * 512 + skq * 4]
                               : float4{0.f, 0.f, 0.f, 0.f};
        }

        for (int ch = 0; ch < 16; ++ch) {
#pragma unroll
            for (int p = 0; p < 8; p++) {
                int r = p * 32 + srow;
                int kb = skq * 4;
                xt[(kb + 0) * XTS + r] = xreg[p].x;
                xt[(kb + 1) * XTS + r] = xreg[p].y;
                xt[(kb + 2) * XTS + r] = xreg[p].z;
                xt[(kb + 3) * XTS + r] = xreg[p].w;
            }
            __syncthreads();

            if (ch < 15) {
                int k0n = (ch + 1) * KCH;
#pragma unroll
                for (int p = 0; p < 8; p++) {
                    int gr = rowBase + p * 32 + srow;
                    xreg[p] = (gr < n) ? *(const float4*)&X[(size_t)gr * 512 + k0n + skq * 4]
                                       : float4{0.f, 0.f, 0.f, 0.f};
                }
            }

#pragma unroll
            for (int k = 0; k < KCH; k++) {
                float xv = xt[k * XTS + t];
                const float4* wrow = (const float4*)&W[(size_t)(ch * KCH + k) * 16];
                float4 w0 = wrow[0], w1 = wrow[1], w2 = wrow[2], w3 = wrow[3];
                acc[0]  = fmaf(xv, w0.x, acc[0]);  acc[1]  = fmaf(xv, w0.y, acc[1]);
                acc[2]  = fmaf(xv, w0.z, acc[2]);  acc[3]  = fmaf(xv, w0.w, acc[3]);
                acc[4]  = fmaf(xv, w1.x, acc[4]);  acc[5]  = fmaf(xv, w1.y, acc[5]);
                acc[6]  = fmaf(xv, w1.z, acc[6]);  acc[7]  = fmaf(xv, w1.w, acc[7]);
                acc[8]  = fmaf(xv, w2.x, acc[8]);  acc[9]  = fmaf(xv, w2.y, acc[9]);
                acc[10] = fmaf(xv, w2.z, acc[10]); acc[11] = fmaf(xv, w2.w, acc[11]);
                acc[12] = fmaf(xv, w3.x, acc[12]); acc[13] = fmaf(xv, w3.y, acc[13]);
                acc[14] = fmaf(xv, w3.z, acc[14]); acc[15] = fmaf(xv, w3.w, acc[15]);
            }
            __syncthreads();
        }

        if (myRow < n) {
            const float4* bp = (const float4*)B;
            float4 b0 = bp[0], b1 = bp[1], b2 = bp[2], b3 = bp[3];
            float4* o = (float4*)&H[(size_t)myRow * 16];
            o[0] = float4{acc[0] + b0.x, acc[1] + b0.y, acc[2] + b0.z, acc[3] + b0.w};
            o[1] = float4{acc[4] + b1.x, acc[5] + b1.y, acc[6] + b1.z, acc[7] + b1.w};
            o[2] = float4{acc[8] + b2.x, acc[9] + b2.y, acc[10] + b2.z, acc[11] + b2.w};
            o[3] = float4{acc[12] + b3.x, acc[13] + b3.y, acc[14] + b3.z, acc[15] + b3.w};
        }
    } else {
        // ---- scatter path: LDS bucket sort -> coalesced burst writes ----
        unsigned int*   stageD = (unsigned int*)smem;            // 4096 * 4B
        unsigned short* stageS = (unsigned short*)(smem + 16384); // 4096 * 2B
        int* cntD  = (int*)(smem + 24576);
        int* cntS  = (int*)(smem + 25600);
        int* rsvD  = (int*)(smem + 26624);
        int* rsvS  = (int*)(smem + 27648);
        int* scanD = (int*)(smem + 28672);
        int* scanS = (int*)(smem + 29696);
        int* ps    = (int*)(smem + 30720);

        int bb = blockIdx.x - nG1;
        int lo = bb * CHK, hi = min(E, lo + CHK);

        cntD[t] = 0; cntS[t] = 0;
        __syncthreads();
        // A: histogram
        for (int i = lo + t; i < hi; i += 256) {
            atomicAdd(&cntD[dst[i] >> BSH], 1);
            atomicAdd(&cntS[src[i] >> BSH], 1);
        }
        __syncthreads();
        // B1: scan D
        int vD = cntD[t];
        ps[t] = vD; __syncthreads();
        for (int o = 1; o < 256; o <<= 1) {
            int u = (t >= o) ? ps[t - o] : 0; __syncthreads();
            ps[t] += u; __syncthreads();
        }
        scanD[t] = ps[t] - vD;
        if (t < nbk && vD) rsvD[t] = atomicAdd(&curD[t], vD);
        __syncthreads();
        // B2: scan S
        int vS = cntS[t];
        ps[t] = vS; __syncthreads();
        for (int o = 1; o < 256; o <<= 1) {
            int u = (t >= o) ? ps[t - o] : 0; __syncthreads();
            ps[t] += u; __syncthreads();
        }
        scanS[t] = ps[t] - vS;
        if (t < nbk && vS) rsvS[t] = atomicAdd(&curS[t], vS);
        cntD[t] = 0; cntS[t] = 0;
        __syncthreads();
        // C: place into LDS stages, sorted by bucket (re-read is L2-hot)
        for (int i = lo + t; i < hi; i += 256) {
            int s = src[i], d = dst[i];
            int bd = d >> BSH;
            int pd = scanD[bd] + atomicAdd(&cntD[bd], 1);
            stageD[pd] = ((unsigned int)s << BSH) | (unsigned int)(d & (BSZ - 1));
            int bs = s >> BSH;
            int pp = scanS[bs] + atomicAdd(&cntS[bs], 1);
            stageS[pp] = (unsigned short)(s & (BSZ - 1));
        }
        __syncthreads();
        // D: burst-copy runs to reserved global ranges (coalesced)
        int wave = t >> 6, lane = t & 63;
        for (int b = wave; b < nbk; b += 4) {
            int st = scanD[b], len = cntD[b], g = rsvD[b];
            for (int j = lane; j < len; j += 64) pairs[g + j] = stageD[st + j];
        }
        for (int b = wave; b < nbk; b += 4) {
            int st = scanS[b], len = cntS[b], g = rsvS[b];
            for (int j = lane; j < len; j += 64) sbuf[g + j] = stageS[st + j];
        }
    }
}

// ---------------- dinv (src-degree) + scale h1 -> bf16 hw1 (hw1 = dinv * h1) ----------------

__global__ __launch_bounds__(256) void dinvScale_k(const unsigned short* __restrict__ sbuf,
                                                   const int* __restrict__ curS,
                                                   const float* __restrict__ h1,
                                                   float* __restrict__ dinv,
                                                   unsigned short* __restrict__ hw1, int n) {
    __shared__ int cnt[BSZ];
    __shared__ float dl[BSZ];
    int b = blockIdx.x, t = threadIdx.x;
    cnt[t] = 0; cnt[t + 256] = 0;
    __syncthreads();
    int lo = b * CAP, hi = curS[b];
    for (int i = lo + t; i < hi; i += 256) atomicAdd(&cnt[sbuf[i]], 1);
    __syncthreads();
    int n0 = b * BSZ + t, n1 = n0 + 256;
    float d0 = rsqrtf((float)(1 + cnt[t]));
    float d1 = rsqrtf((float)(1 + cnt[t + 256]));
    dl[t] = d0; dl[t + 256] = d1;
    if (n0 < n) dinv[n0] = d0;
    if (n1 < n) dinv[n1] = d1;
    __syncthreads();
    int rows = min(BSZ, n - b * BSZ);
    int lim4 = rows * 4;                      // float4 units in this bucket
    size_t base = (size_t)b * BSZ * 16;
#pragma unroll
    for (int j = 0; j < 8; j++) {
        int i4 = j * 256 + t;
        if (i4 < lim4) {
            float4 v = *(const float4*)&h1[base + (size_t)i4 * 4];
            float d = dl[i4 >> 2];
            ushort4 u;
            u.x = f2bf(v.x * d); u.y = f2bf(v.y * d);
            u.z = f2bf(v.z * d); u.w = f2bf(v.w * d);
            *(ushort4*)&hw1[base + (size_t)i4 * 4] = u;
        }
    }
}

// ---------------- CSR build + rowsum[d] = dd*(dd + sum_{s in N_in(d)} dinv[s]) ----------------

__global__ __launch_bounds__(256) void build_k(const unsigned int* __restrict__ pairs,
                                               const int* __restrict__ curD,
                                               const float* __restrict__ dinv,
                                               int* __restrict__ rowPtr, int* __restrict__ cntD,
                                               int* __restrict__ col, float* __restrict__ rowsum,
                                               int n) {
    __shared__ int cnt[BSZ];
    __shared__ int off[BSZ];
    __shared__ int ps[256];
    __shared__ float lsum[BSZ];
    int b = blockIdx.x, t = threadIdx.x;
    cnt[t] = 0; cnt[t + 256] = 0;
    lsum[t] = 0.f; lsum[t + 256] = 0.f;
    __syncthreads();
    int lo = b * CAP, hi = curD[b];
    for (int i = lo + t; i < hi; i += 256) atomicAdd(&cnt[pairs[i] & (BSZ - 1)], 1);
    __syncthreads();
    int c0 = cnt[2 * t], c1 = cnt[2 * t + 1];
    ps[t] = c0 + c1;
    __syncthreads();
    for (int o = 1; o < 256; o <<= 1) {
        int u = (t >= o) ? ps[t - o] : 0; __syncthreads();
        ps[t] += u; __syncthreads();
    }
    int ex = ps[t] - (c0 + c1);
    off[2 * t] = ex; off[2 * t + 1] = ex + c0;
    __syncthreads();
    int n0 = b * BSZ + t, n1 = n0 + 256;
    if (n0 < n) { rowPtr[n0] = lo + off[t]; cntD[n0] = cnt[t]; }
    if (n1 < n) { rowPtr[n1] = lo + off[t + 256]; cntD[n1] = cnt[t + 256]; }
    __syncthreads();
    cnt[t] = 0; cnt[t + 256] = 0;
    __syncthreads();
    for (int i = lo + t; i < hi; i += 256) {  // L2-hot re-read
        unsigned int p = pairs[i];
        int l = p & (BSZ - 1);
        int s = (int)(p >> BSH);
        int pos = lo + off[l] + atomicAdd(&cnt[l], 1);
        col[pos] = s;
        atomicAdd(&lsum[l], dinv[s]);
    }
    __syncthreads();
    if (n0 < n) { float dd = dinv[n0]; rowsum[n0] = dd * (dd + lsum[t]); }
    if (n1 < n) { float dd = dinv[n1]; rowsum[n1] = dd * (dd + lsum[t + 256]); }
}

// ---------------- aggregation on premultiplied bf16 features ----------------
// A[d] = hw[d] + sum_s hw[s];  4 lanes/edge, ushort4 (8B) per lane, 2-way unroll

__device__ __forceinline__ float4 gather_agg(const unsigned short* __restrict__ HW,
                                             const int* __restrict__ col,
                                             int start, int c, int node, int eg, int q) {
    float4 a0 = {0.f, 0.f, 0.f, 0.f}, a1 = {0.f, 0.f, 0.f, 0.f};
    int i = eg;
    for (; i + 16 < c; i += 32) {
        int s0 = col[start + i];
        int s1 = col[start + i + 16];
        ushort4 u0 = *(const ushort4*)&HW[(size_t)s0 * 16 + q * 4];
        ushort4 u1 = *(const ushort4*)&HW[(size_t)s1 * 16 + q * 4];
        a0.x += b2f(u0.x); a0.y += b2f(u0.y); a0.z += b2f(u0.z); a0.w += b2f(u0.w);
        a1.x += b2f(u1.x); a1.y += b2f(u1.y); a1.z += b2f(u1.z); a1.w += b2f(u1.w);
    }
    if (i < c) {
        int s0 = col[start + i];
        ushort4 u0 = *(const ushort4*)&HW[(size_t)s0 * 16 + q * 4];
        a0.x += b2f(u0.x); a0.y += b2f(u0.y); a0.z += b2f(u0.z); a0.w += b2f(u0.w);
    }
    if (eg == 0) {  // self loop
        ushort4 us = *(const ushort4*)&HW[(size_t)node * 16 + q * 4];
        a1.x += b2f(us.x); a1.y += b2f(us.y); a1.z += b2f(us.z); a1.w += b2f(us.w);
    }
    a0.x += a1.x; a0.y += a1.y; a0.z += a1.z; a0.w += a1.w;
#pragma unroll
    for (int off = 4; off < 64; off <<= 1) {
        a0.x += __shfl_xor(a0.x, off, 64);
        a0.y += __shfl_xor(a0.y, off, 64);
        a0.z += __shfl_xor(a0.z, off, 64);
        a0.w += __shfl_xor(a0.w, off, 64);
    }
    return a0;
}

// layer-1: out = bf16( dinv * relu(dinv * A) )   (premultiplied for layer 2)
__global__ void agg1_k(const unsigned short* __restrict__ HW, const float* __restrict__ dinv,
                       const int* __restrict__ col, const int* __restrict__ rowPtr,
                       const int* __restrict__ cnt, unsigned short* __restrict__ out, int n) {
    int lane = threadIdx.x & 63;
    int node = (blockIdx.x * blockDim.x + threadIdx.x) >> 6;
    if (node >= n) return;
    int eg = lane >> 2, q = lane & 3;
    int start = rowPtr[node], c = cnt[node];
    float4 A = gather_agg(HW, col, start, c, node, eg, q);
    if (eg == 0) {
        float dd = dinv[node];
        ushort4 u;
        u.x = f2bf(dd * fmaxf(dd * A.x, 0.f)); u.y = f2bf(dd * fmaxf(dd * A.y, 0.f));
        u.z = f2bf(dd * fmaxf(dd * A.z, 0.f)); u.w = f2bf(dd * fmaxf(dd * A.w, 0.f));
        *(ushort4*)&out[(size_t)node * 16 + q * 4] = u;
    }
}

// layer-2 aggregation fused with logits + log_softmax
__global__ void agg2f_k(const unsigned short* __restrict__ HW, const float* __restrict__ dinv,
                        const int* __restrict__ col, const int* __restrict__ rowPtr,
                        const int* __restrict__ cnt, const float* __restrict__ rowsum,
                        const float* __restrict__ W2, const float* __restrict__ B2,
                        float* __restrict__ out, int n, int nc) {
    int lane = threadIdx.x & 63;
    int node = (blockIdx.x * blockDim.x + threadIdx.x) >> 6;
    if (node >= n) return;
    int eg = lane >> 2, q = lane & 3;
    int start = rowPtr[node], c = cnt[node];
    float4 A = gather_agg(HW, col, start, c, node, eg, q);
    float dd = dinv[node];
    A.x *= dd; A.y *= dd; A.z *= dd; A.w *= dd;   // a2 features, all lanes hold quad q
    float f[16];
    f[0]  = __shfl(A.x, 0, 64); f[1]  = __shfl(A.y, 0, 64);
    f[2]  = __shfl(A.z, 0, 64); f[3]  = __shfl(A.w, 0, 64);
    f[4]  = __shfl(A.x, 1, 64); f[5]  = __shfl(A.y, 1, 64);
    f[6]  = __shfl(A.z, 1, 64); f[7]  = __shfl(A.w, 1, 64);
    f[8]  = __shfl(A.x, 2, 64); f[9]  = __shfl(A.y, 2, 64);
    f[10] = __shfl(A.z, 2, 64); f[11] = __shfl(A.w, 2, 64);
    f[12] = __shfl(A.x, 3, 64); f[13] = __shfl(A.y, 3, 64);
    f[14] = __shfl(A.z, 3, 64); f[15] = __shfl(A.w, 3, 64);
    float logit = -1e30f;
    if (lane < nc) {
        logit = rowsum[node] * B2[lane];
#pragma unroll
        for (int k = 0; k < 16; k++) logit = fmaf(f[k], W2[k * nc + lane], logit);
    }
    float m = logit;
#pragma unroll
    for (int off = 1; off < 64; off <<= 1) m = fmaxf(m, __shfl_xor(m, off, 64));
    float e = (lane < nc) ? __expf(logit - m) : 0.f;
    float s = e;
#pragma unroll
    for (int off = 1; off < 64; off <<= 1) s += __shfl_xor(s, off, 64);
    if (lane < nc) out[(size_t)node * nc + lane] = logit - m - __logf(s);
}

// ---------------- launch ----------------

extern "C" void kernel_launch(void* const* d_in, const int* in_sizes, int n_in,
                              void* d_out, int out_size, void* d_ws, size_t ws_size,
                              hipStream_t stream) {
    const float* X  = (const float*)d_in[0];
    const int*   EI = (const int*)d_in[1];
    const float* W1 = (const float*)d_in[2];
    const float* B1 = (const float*)d_in[3];
    const float* W2 = (const float*)d_in[4];
    const float* B2 = (const float*)d_in[5];
    float* out = (float*)d_out;

    int NH = in_sizes[3];            // 16
    int NC = in_sizes[5];            // 40
    int NF = in_sizes[2] / NH;       // 512
    int n  = in_sizes[0] / NF;       // 100000
    int E  = in_sizes[1] / 2;        // 3200000
    const int* src = EI;
    const int* dst = EI + E;
    int nbk = (n + BSZ - 1) >> BSH;  // 196

    char* ws = (char*)d_ws;
    size_t o = 0;
    auto alloc = [&](size_t bytes) { size_t r = o; o = (o + bytes + 255) & ~(size_t)255; return r; };
    size_t o_dinv   = alloc((size_t)n * 4);
    size_t o_rowPtr = alloc((size_t)n * 4);
    size_t o_cntD   = alloc((size_t)n * 4);
    size_t o_rsum   = alloc((size_t)n * 4);
    size_t o_curD   = alloc(1024);
    size_t o_curS   = alloc(1024);
    size_t o_pairs  = alloc((size_t)nbk * CAP * 4);
    size_t o_sbuf   = alloc((size_t)nbk * CAP * 2);
    size_t o_col    = alloc((size_t)nbk * CAP * 4);
    size_t o_h1     = alloc((size_t)n * 16 * 4);   // fp32 gemm out (pre-scale)
    size_t o_hw1    = alloc((size_t)n * 16 * 2);   // bf16 dinv*h1
    size_t o_a1w    = alloc((size_t)n * 16 * 2);   // bf16 dinv*relu(layer1)

    float* dinv  = (float*)(ws + o_dinv);
    int* rowPtr  = (int*)(ws + o_rowPtr);
    int* cntD    = (int*)(ws + o_cntD);
    float* rsum  = (float*)(ws + o_rsum);
    int* curD    = (int*)(ws + o_curD);
    int* curS    = (int*)(ws + o_curS);
    unsigned int* pairs   = (unsigned int*)(ws + o_pairs);
    unsigned short* sbuf  = (unsigned short*)(ws + o_sbuf);
    int* col     = (int*)(ws + o_col);
    float* h1    = (float*)(ws + o_h1);
    unsigned short* hw1 = (unsigned short*)(ws + o_hw1);
    unsigned short* a1w = (unsigned short*)(ws + o_a1w);

    init_k<<<1, 256, 0, stream>>>(curD, curS, nbk);

    int NBLK = (E + CHK - 1) / CHK;   // 782
    int nG1 = (n + 255) / 256;        // 391
    fused_gs_k<<<nG1 + NBLK, 256, 0, stream>>>(X, W1, B1, h1, n, nG1,
                                               src, dst, E, curD, curS,
                                               pairs, sbuf, nbk);
    dinvScale_k<<<nbk, 256, 0, stream>>>(sbuf, curS, h1, dinv, hw1, n);
    build_k<<<nbk, 256, 0, stream>>>(pairs, curD, dinv, rowPtr, cntD, col, rsum, n);

    int aggGrid = (n + 3) / 4;  // one wave per node, 4 waves/block
    agg1_k<<<aggGrid, 256, 0, stream>>>(hw1, dinv, col, rowPtr, cntD, a1w, n);
    agg2f_k<<<aggGrid, 256, 0, stream>>>(a1w, dinv, col, rowPtr, cntD, rsum, W2, B2, out, n, NC);
}